// Round 1
// baseline (6664.235 us; speedup 1.0000x reference)
//
#include <hip/hip_runtime.h>

#define N_NODESC 50000
#define N_EDGESC 800000
#define XD 64
#define HIDD 128
#define CTXD 64
#define OUTD 64
#define K2 194   // 64 + 64 + 2 + 64

// ---------------------------------------------------------------------------
// Kernel 1: per-edge L1 message MLP (2 -> 128 -> 64) fused with atomic
// segment-sum into sum1[row] and edge count cnt[row].
// b2 of the MLP is NOT added here (added after the mean in ctx_nodes).
// ---------------------------------------------------------------------------
__global__ __launch_bounds__(256) void l1_edges(
    const int* __restrict__ ei, const float* __restrict__ pos,
    const float* __restrict__ w1, const float* __restrict__ b1,
    const float* __restrict__ w2,
    float* __restrict__ sum1, float* __restrict__ cnt)
{
    __shared__ float w1s[3 * HIDD];      // w1[0][:], w1[1][:], b1[:]
    __shared__ float w2s[HIDD * CTXD];   // [128][64]
    for (int i = threadIdx.x; i < 2 * HIDD; i += 256) w1s[i] = w1[i];
    for (int i = threadIdx.x; i < HIDD; i += 256) w1s[2 * HIDD + i] = b1[i];
    for (int i = threadIdx.x; i < HIDD * CTXD; i += 256) w2s[i] = w2[i];
    __syncthreads();

    int e = blockIdx.x * 256 + threadIdx.x;
    if (e >= N_EDGESC) return;
    int row = ei[e];
    int col = ei[N_EDGESC + e];
    float px = pos[2 * col]     - pos[2 * row];
    float py = pos[2 * col + 1] - pos[2 * row + 1];

    float acc[CTXD];
    #pragma unroll
    for (int k = 0; k < CTXD; ++k) acc[k] = 0.f;

    for (int j = 0; j < HIDD; ++j) {
        float hj = fmaf(py, w1s[HIDD + j], fmaf(px, w1s[j], w1s[2 * HIDD + j]));
        hj = fmaxf(hj, 0.f);
        const float4* wr = reinterpret_cast<const float4*>(&w2s[j * CTXD]);
        #pragma unroll
        for (int k4 = 0; k4 < CTXD / 4; ++k4) {
            float4 w = wr[k4];
            acc[4 * k4 + 0] = fmaf(hj, w.x, acc[4 * k4 + 0]);
            acc[4 * k4 + 1] = fmaf(hj, w.y, acc[4 * k4 + 1]);
            acc[4 * k4 + 2] = fmaf(hj, w.z, acc[4 * k4 + 2]);
            acc[4 * k4 + 3] = fmaf(hj, w.w, acc[4 * k4 + 3]);
        }
    }
    float* dst = sum1 + (size_t)row * CTXD;
    #pragma unroll
    for (int k = 0; k < CTXD; ++k) unsafeAtomicAdd(dst + k, acc[k]);
    unsafeAtomicAdd(cnt + row, 1.0f);
}

// ---------------------------------------------------------------------------
// Kernel 2: per-node ctx = MLP(mean(m1) + l1m_b2)  (64 -> 128 -> 64)
// ---------------------------------------------------------------------------
__global__ __launch_bounds__(256) void ctx_nodes(
    const float* __restrict__ sum1, const float* __restrict__ cnt,
    const float* __restrict__ mb2,   // l1m_b2 [64]
    const float* __restrict__ aw1,   // [64][128]
    const float* __restrict__ ab1,   // [128]
    const float* __restrict__ aw2,   // [128][64]
    const float* __restrict__ ab2,   // [64]
    float* __restrict__ ctxout)
{
    __shared__ float w1t[HIDD * CTXD];   // transposed: [j][i], 32 KB
    for (int idx = threadIdx.x; idx < CTXD * HIDD; idx += 256) {
        int i = idx >> 7;            // input dim 0..63
        int j = idx & (HIDD - 1);    // hidden dim 0..127
        w1t[j * CTXD + i] = aw1[idx];
    }
    __syncthreads();

    int n = blockIdx.x * 256 + threadIdx.x;
    if (n >= N_NODESC) return;
    float inv = 1.0f / fmaxf(cnt[n], 1.0f);

    float a[CTXD];
    const float4* s1 = reinterpret_cast<const float4*>(sum1 + (size_t)n * CTXD);
    const float4* mb = reinterpret_cast<const float4*>(mb2);
    #pragma unroll
    for (int i4 = 0; i4 < CTXD / 4; ++i4) {
        float4 v = s1[i4]; float4 m = mb[i4];
        a[4 * i4 + 0] = fmaf(v.x, inv, m.x);
        a[4 * i4 + 1] = fmaf(v.y, inv, m.y);
        a[4 * i4 + 2] = fmaf(v.z, inv, m.z);
        a[4 * i4 + 3] = fmaf(v.w, inv, m.w);
    }

    float o[OUTD];
    const float4* b2v = reinterpret_cast<const float4*>(ab2);
    #pragma unroll
    for (int k4 = 0; k4 < OUTD / 4; ++k4) {
        float4 b = b2v[k4];
        o[4 * k4 + 0] = b.x; o[4 * k4 + 1] = b.y;
        o[4 * k4 + 2] = b.z; o[4 * k4 + 3] = b.w;
    }

    for (int j = 0; j < HIDD; ++j) {
        float hj = ab1[j];
        const float4* wr = reinterpret_cast<const float4*>(&w1t[j * CTXD]);
        #pragma unroll
        for (int i4 = 0; i4 < CTXD / 4; ++i4) {
            float4 w = wr[i4];
            hj = fmaf(a[4 * i4 + 0], w.x, hj);
            hj = fmaf(a[4 * i4 + 1], w.y, hj);
            hj = fmaf(a[4 * i4 + 2], w.z, hj);
            hj = fmaf(a[4 * i4 + 3], w.w, hj);
        }
        hj = fmaxf(hj, 0.f);
        const float4* w2r = reinterpret_cast<const float4*>(aw2 + j * OUTD);
        #pragma unroll
        for (int k4 = 0; k4 < OUTD / 4; ++k4) {
            float4 w = w2r[k4];
            o[4 * k4 + 0] = fmaf(hj, w.x, o[4 * k4 + 0]);
            o[4 * k4 + 1] = fmaf(hj, w.y, o[4 * k4 + 1]);
            o[4 * k4 + 2] = fmaf(hj, w.z, o[4 * k4 + 2]);
            o[4 * k4 + 3] = fmaf(hj, w.w, o[4 * k4 + 3]);
        }
    }
    float4* outp = reinterpret_cast<float4*>(ctxout + (size_t)n * CTXD);
    #pragma unroll
    for (int k4 = 0; k4 < CTXD / 4; ++k4)
        outp[k4] = make_float4(o[4 * k4], o[4 * k4 + 1], o[4 * k4 + 2], o[4 * k4 + 3]);
}

// ---------------------------------------------------------------------------
// Kernel 3: per-edge L2 message MLP (194 -> 128 -> 64) fused with atomic
// segment-sum into sum2[row]. W1 (99 KB) staged in dynamic LDS.
// Hidden layer computed in 4 register passes of 32 so all register-array
// indices are compile-time constants.
// ---------------------------------------------------------------------------
__global__ __launch_bounds__(512) void l2_edges(
    const int* __restrict__ ei, const float* __restrict__ x,
    const float* __restrict__ pos, const float* __restrict__ ctxin,
    const float* __restrict__ w1, const float* __restrict__ b1,
    const float* __restrict__ w2,
    float* __restrict__ sum2)
{
    extern __shared__ float w1s[];   // [194][128] = 99328 B
    for (int i = threadIdx.x; i < K2 * HIDD; i += 512) w1s[i] = w1[i];
    __syncthreads();

    int e = blockIdx.x * 512 + threadIdx.x;
    if (e >= N_EDGESC) return;
    int row = ei[e];
    int col = ei[N_EDGESC + e];
    float px = pos[2 * col]     - pos[2 * row];
    float py = pos[2 * col + 1] - pos[2 * row + 1];
    const float4* xr = reinterpret_cast<const float4*>(x + (size_t)row * XD);
    const float4* xc = reinterpret_cast<const float4*>(x + (size_t)col * XD);
    const float4* cr = reinterpret_cast<const float4*>(ctxin + (size_t)row * CTXD);

    float o[OUTD];
    #pragma unroll
    for (int k = 0; k < OUTD; ++k) o[k] = 0.f;

    const int HB = HIDD / 4;   // 32 hidden units per pass
    for (int pass = 0; pass < 4; ++pass) {
        const int jb = pass * HB;
        float h[HB];
        #pragma unroll
        for (int c = 0; c < HB; ++c) h[c] = b1[jb + c];

        auto accf = [&](float v, const float* rowbase) {
            const float4* wr = reinterpret_cast<const float4*>(rowbase);
            #pragma unroll
            for (int c4 = 0; c4 < HB / 4; ++c4) {
                float4 w = wr[c4];
                h[4 * c4 + 0] = fmaf(v, w.x, h[4 * c4 + 0]);
                h[4 * c4 + 1] = fmaf(v, w.y, h[4 * c4 + 1]);
                h[4 * c4 + 2] = fmaf(v, w.z, h[4 * c4 + 2]);
                h[4 * c4 + 3] = fmaf(v, w.w, h[4 * c4 + 3]);
            }
        };

        // features 0..63: x_i ; features 64..127: x_j - x_i
        for (int i4 = 0; i4 < 16; ++i4) {
            float4 vi = xr[i4];
            float4 vc = xc[i4];
            const float* base0 = &w1s[(4 * i4) * HIDD + jb];
            const float* base1 = &w1s[(64 + 4 * i4) * HIDD + jb];
            accf(vi.x, base0);            accf(vc.x - vi.x, base1);
            accf(vi.y, base0 + HIDD);     accf(vc.y - vi.y, base1 + HIDD);
            accf(vi.z, base0 + 2 * HIDD); accf(vc.z - vi.z, base1 + 2 * HIDD);
            accf(vi.w, base0 + 3 * HIDD); accf(vc.w - vi.w, base1 + 3 * HIDD);
        }
        // features 128,129: pdiff
        accf(px, &w1s[128 * HIDD + jb]);
        accf(py, &w1s[129 * HIDD + jb]);
        // features 130..193: ctx[row]
        for (int i4 = 0; i4 < 16; ++i4) {
            float4 v = cr[i4];
            const float* base = &w1s[(130 + 4 * i4) * HIDD + jb];
            accf(v.x, base);
            accf(v.y, base + HIDD);
            accf(v.z, base + 2 * HIDD);
            accf(v.w, base + 3 * HIDD);
        }
        // partial second layer for these 32 hidden units
        #pragma unroll
        for (int c = 0; c < HB; ++c) {
            float hj = fmaxf(h[c], 0.f);
            const float4* w2r = reinterpret_cast<const float4*>(w2 + (jb + c) * OUTD);
            #pragma unroll
            for (int k4 = 0; k4 < OUTD / 4; ++k4) {
                float4 w = w2r[k4];
                o[4 * k4 + 0] = fmaf(hj, w.x, o[4 * k4 + 0]);
                o[4 * k4 + 1] = fmaf(hj, w.y, o[4 * k4 + 1]);
                o[4 * k4 + 2] = fmaf(hj, w.z, o[4 * k4 + 2]);
                o[4 * k4 + 3] = fmaf(hj, w.w, o[4 * k4 + 3]);
            }
        }
    }
    float* dst = sum2 + (size_t)row * OUTD;
    #pragma unroll
    for (int k = 0; k < OUTD; ++k) unsafeAtomicAdd(dst + k, o[k]);
}

// ---------------------------------------------------------------------------
// Kernel 4: per-node out = MLP([x, mean(m2)+l2m_b2])  (128 -> 128 -> 64)
// ---------------------------------------------------------------------------
__global__ __launch_bounds__(256) void out_nodes(
    const float* __restrict__ x, const float* __restrict__ sum2,
    const float* __restrict__ cnt,
    const float* __restrict__ mb2,  // l2m_b2 [64]
    const float* __restrict__ aw1,  // [128][128]
    const float* __restrict__ ab1,  // [128]
    const float* __restrict__ aw2,  // [128][64]
    const float* __restrict__ ab2,  // [64]
    float* __restrict__ out)
{
    extern __shared__ float w1t[];   // transposed [j][i] = 64 KB
    for (int idx = threadIdx.x; idx < HIDD * HIDD; idx += 256) {
        int i = idx >> 7;
        int j = idx & (HIDD - 1);
        w1t[j * HIDD + i] = aw1[idx];
    }
    __syncthreads();

    int n = blockIdx.x * 256 + threadIdx.x;
    if (n >= N_NODESC) return;
    float inv = 1.0f / fmaxf(cnt[n], 1.0f);

    float a[HIDD];
    const float4* xv = reinterpret_cast<const float4*>(x + (size_t)n * XD);
    #pragma unroll
    for (int i4 = 0; i4 < XD / 4; ++i4) {
        float4 v = xv[i4];
        a[4 * i4 + 0] = v.x; a[4 * i4 + 1] = v.y;
        a[4 * i4 + 2] = v.z; a[4 * i4 + 3] = v.w;
    }
    const float4* s2 = reinterpret_cast<const float4*>(sum2 + (size_t)n * OUTD);
    const float4* mb = reinterpret_cast<const float4*>(mb2);
    #pragma unroll
    for (int i4 = 0; i4 < OUTD / 4; ++i4) {
        float4 v = s2[i4]; float4 m = mb[i4];
        a[XD + 4 * i4 + 0] = fmaf(v.x, inv, m.x);
        a[XD + 4 * i4 + 1] = fmaf(v.y, inv, m.y);
        a[XD + 4 * i4 + 2] = fmaf(v.z, inv, m.z);
        a[XD + 4 * i4 + 3] = fmaf(v.w, inv, m.w);
    }

    float o[OUTD];
    const float4* b2v = reinterpret_cast<const float4*>(ab2);
    #pragma unroll
    for (int k4 = 0; k4 < OUTD / 4; ++k4) {
        float4 b = b2v[k4];
        o[4 * k4 + 0] = b.x; o[4 * k4 + 1] = b.y;
        o[4 * k4 + 2] = b.z; o[4 * k4 + 3] = b.w;
    }

    for (int j = 0; j < HIDD; ++j) {
        float hj = ab1[j];
        const float4* wr = reinterpret_cast<const float4*>(&w1t[j * HIDD]);
        #pragma unroll
        for (int i4 = 0; i4 < HIDD / 4; ++i4) {
            float4 w = wr[i4];
            hj = fmaf(a[4 * i4 + 0], w.x, hj);
            hj = fmaf(a[4 * i4 + 1], w.y, hj);
            hj = fmaf(a[4 * i4 + 2], w.z, hj);
            hj = fmaf(a[4 * i4 + 3], w.w, hj);
        }
        hj = fmaxf(hj, 0.f);
        const float4* w2r = reinterpret_cast<const float4*>(aw2 + j * OUTD);
        #pragma unroll
        for (int k4 = 0; k4 < OUTD / 4; ++k4) {
            float4 w = w2r[k4];
            o[4 * k4 + 0] = fmaf(hj, w.x, o[4 * k4 + 0]);
            o[4 * k4 + 1] = fmaf(hj, w.y, o[4 * k4 + 1]);
            o[4 * k4 + 2] = fmaf(hj, w.z, o[4 * k4 + 2]);
            o[4 * k4 + 3] = fmaf(hj, w.w, o[4 * k4 + 3]);
        }
    }
    float4* outp = reinterpret_cast<float4*>(out + (size_t)n * OUTD);
    #pragma unroll
    for (int k4 = 0; k4 < OUTD / 4; ++k4)
        outp[k4] = make_float4(o[4 * k4], o[4 * k4 + 1], o[4 * k4 + 2], o[4 * k4 + 3]);
}

// ---------------------------------------------------------------------------
extern "C" void kernel_launch(void* const* d_in, const int* in_sizes, int n_in,
                              void* d_out, int out_size, void* d_ws, size_t ws_size,
                              hipStream_t stream)
{
    const float* x      = (const float*)d_in[0];
    const float* pos    = (const float*)d_in[1];
    const int*   ei     = (const int*)  d_in[2];
    const float* l1m_w1 = (const float*)d_in[3];
    const float* l1m_b1 = (const float*)d_in[4];
    const float* l1m_w2 = (const float*)d_in[5];
    const float* l1m_b2 = (const float*)d_in[6];
    const float* l1a_w1 = (const float*)d_in[7];
    const float* l1a_b1 = (const float*)d_in[8];
    const float* l1a_w2 = (const float*)d_in[9];
    const float* l1a_b2 = (const float*)d_in[10];
    const float* l2m_w1 = (const float*)d_in[11];
    const float* l2m_b1 = (const float*)d_in[12];
    const float* l2m_w2 = (const float*)d_in[13];
    const float* l2m_b2 = (const float*)d_in[14];
    const float* l2a_w1 = (const float*)d_in[15];
    const float* l2a_b1 = (const float*)d_in[16];
    const float* l2a_w2 = (const float*)d_in[17];
    const float* l2a_b2 = (const float*)d_in[18];

    float* ws   = (float*)d_ws;
    float* cnt  = ws;                                  // [N]
    float* sum1 = ws + N_NODESC;                       // [N][64]
    float* sum2 = sum1 + (size_t)N_NODESC * CTXD;      // [N][64]
    float* ctxb = sum2 + (size_t)N_NODESC * OUTD;      // [N][64]

    // zero cnt + sum1 + sum2 (contiguous) every call
    size_t zero_bytes = (size_t)(N_NODESC + N_NODESC * CTXD + N_NODESC * OUTD) * sizeof(float);
    hipMemsetAsync(d_ws, 0, zero_bytes, stream);

    // allow >64KB dynamic LDS
    hipFuncSetAttribute((const void*)l2_edges,
                        hipFuncAttributeMaxDynamicSharedMemorySize, K2 * HIDD * 4);
    hipFuncSetAttribute((const void*)out_nodes,
                        hipFuncAttributeMaxDynamicSharedMemorySize, HIDD * HIDD * 4);

    l1_edges<<<(N_EDGESC + 255) / 256, 256, 0, stream>>>(
        ei, pos, l1m_w1, l1m_b1, l1m_w2, sum1, cnt);
    ctx_nodes<<<(N_NODESC + 255) / 256, 256, 0, stream>>>(
        sum1, cnt, l1m_b2, l1a_w1, l1a_b1, l1a_w2, l1a_b2, ctxb);
    l2_edges<<<(N_EDGESC + 511) / 512, 512, K2 * HIDD * 4, stream>>>(
        ei, x, pos, ctxb, l2m_w1, l2m_b1, l2m_w2, sum2);
    out_nodes<<<(N_NODESC + 255) / 256, 256, HIDD * HIDD * 4, stream>>>(
        x, sum2, cnt, l2m_b2, l2a_w1, l2a_b1, l2a_w2, l2a_b2, (float*)d_out);
}

// Round 2
// 757.787 us; speedup vs baseline: 8.7943x; 8.7943x over previous
//
#include <hip/hip_runtime.h>

#define N_NODESC 50000
#define N_EDGESC 800000
#define XD 64
#define HIDD 128
#define CTXD 64
#define OUTD 64

typedef __bf16 bf16x8 __attribute__((ext_vector_type(8)));
typedef float f32x4 __attribute__((ext_vector_type(4)));

__device__ __forceinline__ unsigned short f2bf(float x) {
    unsigned u = __builtin_bit_cast(unsigned, x);
    unsigned r = u + 0x7FFFu + ((u >> 16) & 1u);
    return (unsigned short)(r >> 16);
}
__device__ __forceinline__ unsigned int pack2(float lo, float hi) {
    return (unsigned int)f2bf(lo) | ((unsigned int)f2bf(hi) << 16);
}

// ---------------------------------------------------------------------------
// Prep: bf16 weight transposes.
// w1t2: [128 n][224 k] bf16, feature order [x_i(0..63), dx(64..127),
//        ctx(128..191), pd(192,193), zeros(194..223)]
// w2t2: [64 n][128 k] bf16 = l2m_w2^T ;  w2t1: [64][128] = l1m_w2^T
// ---------------------------------------------------------------------------
__global__ void prep_weights(const float* __restrict__ l2m_w1,
                             const float* __restrict__ l2m_w2,
                             const float* __restrict__ l1m_w2,
                             unsigned short* __restrict__ w1t2,
                             unsigned short* __restrict__ w2t2,
                             unsigned short* __restrict__ w2t1)
{
    int i0 = blockIdx.x * 256 + threadIdx.x;
    int stride = gridDim.x * 256;
    for (int idx = i0; idx < 128 * 224; idx += stride) {
        int n = idx / 224, k = idx - n * 224;
        float v = 0.f;
        if (k < 194) {
            int kk = (k < 128) ? k : (k < 192 ? k + 2 : (k == 192 ? 128 : 129));
            v = l2m_w1[kk * 128 + n];
        }
        w1t2[idx] = f2bf(v);
    }
    for (int idx = i0; idx < 64 * 128; idx += stride) {
        int n = idx >> 7, k = idx & 127;
        w2t2[idx] = f2bf(l2m_w2[k * 64 + n]);
        w2t1[idx] = f2bf(l1m_w2[k * 64 + n]);
    }
}

// ---------------------------------------------------------------------------
// L1 edges: h = relu(pdiff @ w1 + b1) via VALU (K=2), then MFMA GEMM
// h[128x128] @ w2t1^T -> [128x64], atomic segment-sum into sum1 + cnt.
// ---------------------------------------------------------------------------
__global__ __launch_bounds__(512) void l1_mfma(
    const int* __restrict__ ei, const float* __restrict__ pos,
    const float* __restrict__ w1, const float* __restrict__ b1,
    const unsigned short* __restrict__ w2t,
    float* __restrict__ sum1, float* __restrict__ cnt)
{
    __shared__ unsigned short H[128 * 136];   // [edge][hidden] bf16
    __shared__ float pd[128][2];
    __shared__ int rows_s[128];
    const int tid = threadIdx.x;
    const int eb = blockIdx.x * 128;

    if (tid < 128) {
        int e = eb + tid;
        int ri = ei[e], ci = ei[N_EDGESC + e];
        rows_s[tid] = ri;
        float2 pr = *(const float2*)(pos + 2 * ri);
        float2 pc = *(const float2*)(pos + 2 * ci);
        pd[tid][0] = pc.x - pr.x;
        pd[tid][1] = pc.y - pr.y;
        unsafeAtomicAdd(cnt + ri, 1.0f);
    }
    __syncthreads();

    {   // hidden layer, 4 threads per edge, 32 hidden units each
        int e_loc = tid >> 2, part = tid & 3;
        float px = pd[e_loc][0], py = pd[e_loc][1];
        int jb = part * 32;
        unsigned int* Hw = (unsigned int*)H + e_loc * 68 + (jb >> 1);
        #pragma unroll
        for (int q = 0; q < 8; ++q) {
            float4 wa = *(const float4*)(w1 + jb + 4 * q);
            float4 wb = *(const float4*)(w1 + 128 + jb + 4 * q);
            float4 bb = *(const float4*)(b1 + jb + 4 * q);
            float h0 = fmaxf(fmaf(px, wa.x, fmaf(py, wb.x, bb.x)), 0.f);
            float h1 = fmaxf(fmaf(px, wa.y, fmaf(py, wb.y, bb.y)), 0.f);
            float h2 = fmaxf(fmaf(px, wa.z, fmaf(py, wb.z, bb.z)), 0.f);
            float h3 = fmaxf(fmaf(px, wa.w, fmaf(py, wb.w, bb.w)), 0.f);
            Hw[2 * q]     = pack2(h0, h1);
            Hw[2 * q + 1] = pack2(h2, h3);
        }
    }
    __syncthreads();

    const int lane = tid & 63;
    const int l15 = lane & 15, l4 = lane >> 4;
    const int wave = tid >> 6;
    const int mh = (wave >> 2) * 64;
    const int nw = (wave & 3) * 16;

    f32x4 acc[4];
    #pragma unroll
    for (int m = 0; m < 4; ++m) acc[m] = (f32x4){0.f, 0.f, 0.f, 0.f};

    #pragma unroll
    for (int k = 0; k < 4; ++k) {
        int kb = k * 32 + l4 * 8;
        bf16x8 b = *(const bf16x8*)(w2t + (nw + l15) * 128 + kb);
        #pragma unroll
        for (int m = 0; m < 4; ++m) {
            bf16x8 a = *(const bf16x8*)(H + (mh + m * 16 + l15) * 136 + kb);
            acc[m] = __builtin_amdgcn_mfma_f32_16x16x32_bf16(a, b, acc[m], 0, 0, 0);
        }
    }
    #pragma unroll
    for (int m = 0; m < 4; ++m) {
        int rb = mh + m * 16 + l4 * 4;
        #pragma unroll
        for (int r = 0; r < 4; ++r)
            unsafeAtomicAdd(sum1 + (size_t)rows_s[rb + r] * CTXD + nw + l15, acc[m][r]);
    }
}

// ---------------------------------------------------------------------------
// L2 edges: MFMA GEMM  msg[128x224bf16] @ W1t -> relu -> H[128x128bf16]
//           H @ W2t -> [128x64], atomic segment-sum into sum2.
// Dynamic LDS: A[128][248] | W[128][248] | H[128][136] | rows[128]
// ---------------------------------------------------------------------------
#define A_OFF 0
#define W_OFF 63488
#define H_OFF 126976
#define R_OFF 161792
#define L2_LDS 162304

__global__ __launch_bounds__(512) void l2_mfma(
    const int* __restrict__ ei, const float* __restrict__ x,
    const float* __restrict__ pos, const float* __restrict__ ctxin,
    const unsigned short* __restrict__ w1t, const float* __restrict__ b1,
    const unsigned short* __restrict__ w2t,
    float* __restrict__ sum2)
{
    extern __shared__ char smem[];
    const int tid = threadIdx.x;
    const int eb = blockIdx.x * 128;

    // stage W1t: [128][224] bf16 global -> [128 rows][248 stride] LDS
    {
        const int4* src = (const int4*)w1t;
        for (int i = tid; i < 3584; i += 512) {
            int n = i / 28, c = i - n * 28;
            *(int4*)(smem + W_OFF + n * 496 + c * 16) = src[i];
        }
    }
    // gather A tile: 4 threads per edge
    {
        int e_loc = tid >> 2, part = tid & 3;
        int e = eb + e_loc;
        int ri = ei[e], ci = ei[N_EDGESC + e];
        unsigned int* Aw = (unsigned int*)(smem + A_OFF) + e_loc * 124;
        if (part == 0) {
            const float4* xs = (const float4*)(x + (size_t)ri * XD);
            #pragma unroll
            for (int q = 0; q < 16; ++q) {
                float4 v = xs[q];
                Aw[2 * q]     = pack2(v.x, v.y);
                Aw[2 * q + 1] = pack2(v.z, v.w);
            }
        } else if (part == 1) {
            const float4* xr = (const float4*)(x + (size_t)ri * XD);
            const float4* xc = (const float4*)(x + (size_t)ci * XD);
            #pragma unroll
            for (int q = 0; q < 16; ++q) {
                float4 a = xr[q], b = xc[q];
                Aw[32 + 2 * q]     = pack2(b.x - a.x, b.y - a.y);
                Aw[32 + 2 * q + 1] = pack2(b.z - a.z, b.w - a.w);
            }
        } else if (part == 2) {
            const float4* cs = (const float4*)(ctxin + (size_t)ri * CTXD);
            #pragma unroll
            for (int q = 0; q < 16; ++q) {
                float4 v = cs[q];
                Aw[64 + 2 * q]     = pack2(v.x, v.y);
                Aw[64 + 2 * q + 1] = pack2(v.z, v.w);
            }
        } else {
            ((int*)(smem + R_OFF))[e_loc] = ri;
            float2 pr = *(const float2*)(pos + 2 * ri);
            float2 pc = *(const float2*)(pos + 2 * ci);
            Aw[96] = pack2(pc.x - pr.x, pc.y - pr.y);
            #pragma unroll
            for (int z = 0; z < 15; ++z) Aw[97 + z] = 0u;
        }
    }
    __syncthreads();

    const int lane = tid & 63;
    const int l15 = lane & 15, l4 = lane >> 4;
    const int wave = tid >> 6;
    const int mh = (wave >> 2) * 64;          // edge half
    const int nq = (wave & 3) * 32;           // hidden quad (layer 1)

    f32x4 acc[4][2];
    #pragma unroll
    for (int m = 0; m < 4; ++m)
        #pragma unroll
        for (int n = 0; n < 2; ++n) acc[m][n] = (f32x4){0.f, 0.f, 0.f, 0.f};

    #pragma unroll
    for (int k = 0; k < 7; ++k) {
        int koff = k * 64 + l4 * 16;          // byte offset within row
        bf16x8 b0 = *(const bf16x8*)(smem + W_OFF + (nq + l15) * 496 + koff);
        bf16x8 b1f = *(const bf16x8*)(smem + W_OFF + (nq + 16 + l15) * 496 + koff);
        #pragma unroll
        for (int m = 0; m < 4; ++m) {
            bf16x8 a = *(const bf16x8*)(smem + A_OFF + (mh + m * 16 + l15) * 496 + koff);
            acc[m][0] = __builtin_amdgcn_mfma_f32_16x16x32_bf16(a, b0, acc[m][0], 0, 0, 0);
            acc[m][1] = __builtin_amdgcn_mfma_f32_16x16x32_bf16(a, b1f, acc[m][1], 0, 0, 0);
        }
    }
    // epilogue: +b1, relu, bf16, write H [edge][hidden]
    float bv0 = b1[nq + l15];
    float bv1 = b1[nq + 16 + l15];
    #pragma unroll
    for (int m = 0; m < 4; ++m) {
        int rb = mh + m * 16 + l4 * 4;
        #pragma unroll
        for (int n = 0; n < 2; ++n) {
            float bv = n ? bv1 : bv0;
            int col = nq + n * 16 + l15;
            #pragma unroll
            for (int r = 0; r < 4; ++r) {
                float h = fmaxf(acc[m][n][r] + bv, 0.f);
                *(unsigned short*)(smem + H_OFF + (rb + r) * 272 + col * 2) = f2bf(h);
            }
        }
    }
    __syncthreads();

    // layer 2: H[128x128] @ W2t^T -> [128x64]
    const int nw = (wave & 3) * 16;
    f32x4 acc2[4];
    #pragma unroll
    for (int m = 0; m < 4; ++m) acc2[m] = (f32x4){0.f, 0.f, 0.f, 0.f};

    #pragma unroll
    for (int k = 0; k < 4; ++k) {
        int kb = k * 32 + l4 * 8;
        bf16x8 b = *(const bf16x8*)(w2t + (nw + l15) * 128 + kb);
        #pragma unroll
        for (int m = 0; m < 4; ++m) {
            bf16x8 a = *(const bf16x8*)(smem + H_OFF + (mh + m * 16 + l15) * 272 + kb * 2);
            acc2[m] = __builtin_amdgcn_mfma_f32_16x16x32_bf16(a, b, acc2[m], 0, 0, 0);
        }
    }
    const int* rows_p = (const int*)(smem + R_OFF);
    #pragma unroll
    for (int m = 0; m < 4; ++m) {
        int rb = mh + m * 16 + l4 * 4;
        #pragma unroll
        for (int r = 0; r < 4; ++r)
            unsafeAtomicAdd(sum2 + (size_t)rows_p[rb + r] * OUTD + nw + l15, acc2[m][r]);
    }
}

// ---------------------------------------------------------------------------
// Kernel: per-node ctx = MLP(mean(m1) + l1m_b2)  (64 -> 128 -> 64)  [fp32]
// ---------------------------------------------------------------------------
__global__ __launch_bounds__(256) void ctx_nodes(
    const float* __restrict__ sum1, const float* __restrict__ cnt,
    const float* __restrict__ mb2, const float* __restrict__ aw1,
    const float* __restrict__ ab1, const float* __restrict__ aw2,
    const float* __restrict__ ab2, float* __restrict__ ctxout)
{
    __shared__ float w1t[HIDD * CTXD];
    for (int idx = threadIdx.x; idx < CTXD * HIDD; idx += 256) {
        int i = idx >> 7;
        int j = idx & (HIDD - 1);
        w1t[j * CTXD + i] = aw1[idx];
    }
    __syncthreads();

    int n = blockIdx.x * 256 + threadIdx.x;
    if (n >= N_NODESC) return;
    float inv = 1.0f / fmaxf(cnt[n], 1.0f);

    float a[CTXD];
    const float4* s1 = reinterpret_cast<const float4*>(sum1 + (size_t)n * CTXD);
    const float4* mb = reinterpret_cast<const float4*>(mb2);
    #pragma unroll
    for (int i4 = 0; i4 < CTXD / 4; ++i4) {
        float4 v = s1[i4]; float4 m = mb[i4];
        a[4 * i4 + 0] = fmaf(v.x, inv, m.x);
        a[4 * i4 + 1] = fmaf(v.y, inv, m.y);
        a[4 * i4 + 2] = fmaf(v.z, inv, m.z);
        a[4 * i4 + 3] = fmaf(v.w, inv, m.w);
    }
    float o[OUTD];
    const float4* b2v = reinterpret_cast<const float4*>(ab2);
    #pragma unroll
    for (int k4 = 0; k4 < OUTD / 4; ++k4) {
        float4 b = b2v[k4];
        o[4 * k4 + 0] = b.x; o[4 * k4 + 1] = b.y;
        o[4 * k4 + 2] = b.z; o[4 * k4 + 3] = b.w;
    }
    for (int j = 0; j < HIDD; ++j) {
        float hj = ab1[j];
        const float4* wr = reinterpret_cast<const float4*>(&w1t[j * CTXD]);
        #pragma unroll
        for (int i4 = 0; i4 < CTXD / 4; ++i4) {
            float4 w = wr[i4];
            hj = fmaf(a[4 * i4 + 0], w.x, hj);
            hj = fmaf(a[4 * i4 + 1], w.y, hj);
            hj = fmaf(a[4 * i4 + 2], w.z, hj);
            hj = fmaf(a[4 * i4 + 3], w.w, hj);
        }
        hj = fmaxf(hj, 0.f);
        const float4* w2r = reinterpret_cast<const float4*>(aw2 + j * OUTD);
        #pragma unroll
        for (int k4 = 0; k4 < OUTD / 4; ++k4) {
            float4 w = w2r[k4];
            o[4 * k4 + 0] = fmaf(hj, w.x, o[4 * k4 + 0]);
            o[4 * k4 + 1] = fmaf(hj, w.y, o[4 * k4 + 1]);
            o[4 * k4 + 2] = fmaf(hj, w.z, o[4 * k4 + 2]);
            o[4 * k4 + 3] = fmaf(hj, w.w, o[4 * k4 + 3]);
        }
    }
    float4* outp = reinterpret_cast<float4*>(ctxout + (size_t)n * CTXD);
    #pragma unroll
    for (int k4 = 0; k4 < CTXD / 4; ++k4)
        outp[k4] = make_float4(o[4 * k4], o[4 * k4 + 1], o[4 * k4 + 2], o[4 * k4 + 3]);
}

// ---------------------------------------------------------------------------
// Kernel: per-node out = MLP([x, mean(m2)+l2m_b2])  (128 -> 128 -> 64) [fp32]
// ---------------------------------------------------------------------------
__global__ __launch_bounds__(256) void out_nodes(
    const float* __restrict__ x, const float* __restrict__ sum2,
    const float* __restrict__ cnt, const float* __restrict__ mb2,
    const float* __restrict__ aw1, const float* __restrict__ ab1,
    const float* __restrict__ aw2, const float* __restrict__ ab2,
    float* __restrict__ out)
{
    extern __shared__ float w1t[];
    for (int idx = threadIdx.x; idx < HIDD * HIDD; idx += 256) {
        int i = idx >> 7;
        int j = idx & (HIDD - 1);
        w1t[j * HIDD + i] = aw1[idx];
    }
    __syncthreads();

    int n = blockIdx.x * 256 + threadIdx.x;
    if (n >= N_NODESC) return;
    float inv = 1.0f / fmaxf(cnt[n], 1.0f);

    float a[HIDD];
    const float4* xv = reinterpret_cast<const float4*>(x + (size_t)n * XD);
    #pragma unroll
    for (int i4 = 0; i4 < XD / 4; ++i4) {
        float4 v = xv[i4];
        a[4 * i4 + 0] = v.x; a[4 * i4 + 1] = v.y;
        a[4 * i4 + 2] = v.z; a[4 * i4 + 3] = v.w;
    }
    const float4* s2 = reinterpret_cast<const float4*>(sum2 + (size_t)n * OUTD);
    const float4* mb = reinterpret_cast<const float4*>(mb2);
    #pragma unroll
    for (int i4 = 0; i4 < OUTD / 4; ++i4) {
        float4 v = s2[i4]; float4 m = mb[i4];
        a[XD + 4 * i4 + 0] = fmaf(v.x, inv, m.x);
        a[XD + 4 * i4 + 1] = fmaf(v.y, inv, m.y);
        a[XD + 4 * i4 + 2] = fmaf(v.z, inv, m.z);
        a[XD + 4 * i4 + 3] = fmaf(v.w, inv, m.w);
    }
    float o[OUTD];
    const float4* b2v = reinterpret_cast<const float4*>(ab2);
    #pragma unroll
    for (int k4 = 0; k4 < OUTD / 4; ++k4) {
        float4 b = b2v[k4];
        o[4 * k4 + 0] = b.x; o[4 * k4 + 1] = b.y;
        o[4 * k4 + 2] = b.z; o[4 * k4 + 3] = b.w;
    }
    for (int j = 0; j < HIDD; ++j) {
        float hj = ab1[j];
        const float4* wr = reinterpret_cast<const float4*>(&w1t[j * HIDD]);
        #pragma unroll
        for (int i4 = 0; i4 < HIDD / 4; ++i4) {
            float4 w = wr[i4];
            hj = fmaf(a[4 * i4 + 0], w.x, hj);
            hj = fmaf(a[4 * i4 + 1], w.y, hj);
            hj = fmaf(a[4 * i4 + 2], w.z, hj);
            hj = fmaf(a[4 * i4 + 3], w.w, hj);
        }
        hj = fmaxf(hj, 0.f);
        const float4* w2r = reinterpret_cast<const float4*>(aw2 + j * OUTD);
        #pragma unroll
        for (int k4 = 0; k4 < OUTD / 4; ++k4) {
            float4 w = w2r[k4];
            o[4 * k4 + 0] = fmaf(hj, w.x, o[4 * k4 + 0]);
            o[4 * k4 + 1] = fmaf(hj, w.y, o[4 * k4 + 1]);
            o[4 * k4 + 2] = fmaf(hj, w.z, o[4 * k4 + 2]);
            o[4 * k4 + 3] = fmaf(hj, w.w, o[4 * k4 + 3]);
        }
    }
    float4* outp = reinterpret_cast<float4*>(out + (size_t)n * OUTD);
    #pragma unroll
    for (int k4 = 0; k4 < OUTD / 4; ++k4)
        outp[k4] = make_float4(o[4 * k4], o[4 * k4 + 1], o[4 * k4 + 2], o[4 * k4 + 3]);
}

// ---------------------------------------------------------------------------
extern "C" void kernel_launch(void* const* d_in, const int* in_sizes, int n_in,
                              void* d_out, int out_size, void* d_ws, size_t ws_size,
                              hipStream_t stream)
{
    const float* x      = (const float*)d_in[0];
    const float* pos    = (const float*)d_in[1];
    const int*   ei     = (const int*)  d_in[2];
    const float* l1m_w1 = (const float*)d_in[3];
    const float* l1m_b1 = (const float*)d_in[4];
    const float* l1m_w2 = (const float*)d_in[5];
    const float* l1m_b2 = (const float*)d_in[6];
    const float* l1a_w1 = (const float*)d_in[7];
    const float* l1a_b1 = (const float*)d_in[8];
    const float* l1a_w2 = (const float*)d_in[9];
    const float* l1a_b2 = (const float*)d_in[10];
    const float* l2m_w1 = (const float*)d_in[11];
    const float* l2m_b1 = (const float*)d_in[12];
    const float* l2m_w2 = (const float*)d_in[13];
    const float* l2m_b2 = (const float*)d_in[14];
    const float* l2a_w1 = (const float*)d_in[15];
    const float* l2a_b1 = (const float*)d_in[16];
    const float* l2a_w2 = (const float*)d_in[17];
    const float* l2a_b2 = (const float*)d_in[18];

    float* ws   = (float*)d_ws;
    float* cnt  = ws;
    float* sum1 = ws + N_NODESC;
    float* sum2 = sum1 + (size_t)N_NODESC * CTXD;
    float* ctxb = sum2 + (size_t)N_NODESC * OUTD;
    unsigned short* bfws = (unsigned short*)(ctxb + (size_t)N_NODESC * CTXD);
    unsigned short* w1t2 = bfws;                // 128*224
    unsigned short* w2t2 = w1t2 + 128 * 224;    // 64*128
    unsigned short* w2t1 = w2t2 + 64 * 128;     // 64*128

    size_t zero_bytes = (size_t)(N_NODESC + N_NODESC * CTXD + N_NODESC * OUTD) * sizeof(float);
    hipMemsetAsync(d_ws, 0, zero_bytes, stream);

    hipFuncSetAttribute((const void*)l2_mfma,
                        hipFuncAttributeMaxDynamicSharedMemorySize, L2_LDS);
    hipFuncSetAttribute((const void*)out_nodes,
                        hipFuncAttributeMaxDynamicSharedMemorySize, HIDD * HIDD * 4);

    prep_weights<<<64, 256, 0, stream>>>(l2m_w1, l2m_w2, l1m_w2, w1t2, w2t2, w2t1);

    l1_mfma<<<N_EDGESC / 128, 512, 0, stream>>>(
        ei, pos, l1m_w1, l1m_b1, w2t1, sum1, cnt);

    ctx_nodes<<<(N_NODESC + 255) / 256, 256, 0, stream>>>(
        sum1, cnt, l1m_b2, l1a_w1, l1a_b1, l1a_w2, l1a_b2, ctxb);

    l2_mfma<<<N_EDGESC / 128, 512, L2_LDS, stream>>>(
        ei, x, pos, ctxb, w1t2, l2m_b1, w2t2, sum2);

    out_nodes<<<(N_NODESC + 255) / 256, 256, HIDD * HIDD * 4, stream>>>(
        x, sum2, cnt, l2m_b2, l2a_w1, l2a_b1, l2a_w2, l2a_b2, (float*)d_out);
}